// Round 22
// baseline (4624.458 us; speedup 1.0000x reference)
//
#include <hip/hip_runtime.h>

typedef short short8 __attribute__((ext_vector_type(8)));
typedef float f32x4 __attribute__((ext_vector_type(4)));
typedef unsigned short u16;

static constexpr int BATCH = 2, S = 2048, H = 4096, NHEAD = 32, HDIM = 128;

__device__ __forceinline__ u16 f2b(float f) {
  union { float f; unsigned u; } v; v.f = f;
  return (u16)((v.u + 0x7fffu + ((v.u >> 16) & 1u)) >> 16);
}
__device__ __forceinline__ float b2f(u16 h) {
  union { unsigned u; float f; } v; v.u = ((unsigned)h) << 16;
  return v.f;
}
__device__ __forceinline__ float ex2(float x) {
  return __builtin_amdgcn_exp2f(x);  // v_exp_f32 (base-2 HW exp)
}

__device__ __forceinline__ void gl16(const u16* g, u16* l) {
  __builtin_amdgcn_global_load_lds((__attribute__((address_space(1))) void*)g,
                                   (__attribute__((address_space(3))) void*)l,
                                   16, 0, 0);
}

#define MFMA(acc, a, b) \
  acc = __builtin_amdgcn_mfma_f32_16x16x32_bf16(a, b, acc, 0, 0, 0)

// ---- merged prep: 3x f32->bf16 convert + RoPE table (one launch) ----
__global__ __launch_bounds__(256) void prep(const float* __restrict__ hs,
                                            const float* __restrict__ wpack,
                                            const float* __restrict__ wo,
                                            u16* __restrict__ hs_b,
                                            u16* __restrict__ wpack_b,
                                            u16* __restrict__ wo_b,
                                            float* __restrict__ tab) {
  int b = blockIdx.x;
  if (b < 81920) {
    const float* in; u16* out; size_t off;
    if (b < 16384)      { in = hs;    out = hs_b;    off = (size_t)b * 1024; }
    else if (b < 65536) { in = wpack; out = wpack_b; off = (size_t)(b - 16384) * 1024; }
    else                { in = wo;    out = wo_b;    off = (size_t)(b - 65536) * 1024; }
    size_t i = off + threadIdx.x * 4;
    float4 v = *(const float4*)(in + i);
    ushort4 o = { f2b(v.x), f2b(v.y), f2b(v.z), f2b(v.w) };
    *(ushort4*)(out + i) = o;
  } else {
    int idx = (b - 81920) * 256 + threadIdx.x;  // 512*256 = 2048*64
    int p = idx >> 6, f = idx & 63;
    float freq = __powf(10000.0f, -(float)f * (1.0f / 64.0f));
    float a = (float)p * freq;
    tab[(size_t)p * 128 + f] = cosf(a);
    tab[(size_t)p * 128 + 64 + f] = sinf(a);
  }
}

// ---- 256x256 NT GEMM, r22: SINGLE-buffered (72 KB LDS -> 2 blocks/CU,
// 16 waves/CU). 2 barriers/K-tile: {bar; stage 8 gl16; vmcnt(0); bar;
// frag reads + 32 MFMA free-scheduled}. Cross-block TLP hides the exposed
// stage latency (m114; validated neutral-or-better by flash r20/r21 A/B).
// MODE 0: fused RoPE/V-scatter epilogue, 2-pass E[128][280].
// MODE 1: plain f32 C epilogue.
template <int MODE>
__global__ __launch_bounds__(512, 4) void gemm256(
    const u16* __restrict__ A, const u16* __restrict__ B, void* __restrict__ C,
    int M, int N, int K, const int* __restrict__ pos,
    const float* __restrict__ tab, u16* __restrict__ qr, u16* __restrict__ kr,
    u16* __restrict__ vt) {
  __shared__ u16 SMEM[36864];  // 72 KB: K-loop A(32K)+B(32K); epi E[128][280]
  u16* AL = SMEM;              // A tile 256x64, row-major, row stride 64
  u16* BL = SMEM + 16384;      // B tile 256x64
  const int nbn = N >> 8;
  const int nwg = (M >> 8) * nbn;
  const int bid = blockIdx.x;
  const int wg = (bid & 7) * (nwg >> 3) + (bid >> 3);  // XCD swizzle (nwg%8==0)
  const int bm = wg / nbn, bn = wg % nbn;
  const int tid = threadIdx.x, lane = tid & 63;
  const int w = tid >> 6, wm = w >> 2, wn = w & 3;
  const int hi = lane >> 4, lo = lane & 15;
  const int nk = K >> 6;

  const u16* Abase = A + (size_t)(bm * 256) * K;
  const u16* Bbase = B + (size_t)(bn * 256) * K;

#define BARTOP()                                                               \
  do { __builtin_amdgcn_sched_barrier(0);                                      \
       __builtin_amdgcn_s_barrier();                                           \
       __builtin_amdgcn_sched_barrier(0); } while (0)

  f32x4 acc[8][4] = {};
  short8 af[4][2], bfA[2][2], bfB[2][2];

  for (int t = 0; t < nk; ++t) {
    BARTOP();  // all waves done reading previous tile (reads drained at use)
#pragma unroll
    for (int i = 0; i < 4; ++i) {  // stage A (4 gl16/thread)
      int c = tid + i * 512, r = c >> 3, s = c & 7;
      gl16(Abase + (size_t)r * K + t * 64 + ((s ^ (r & 7)) * 8), &AL[c * 8]);
    }
#pragma unroll
    for (int i = 0; i < 4; ++i) {  // stage B (4 gl16/thread)
      int c = tid + i * 512, r = c >> 3, s = c & 7;
      gl16(Bbase + (size_t)r * K + t * 64 + ((s ^ (r & 7)) * 8), &BL[c * 8]);
    }
    asm volatile("s_waitcnt vmcnt(0)" ::: "memory");
    BARTOP();  // all DMA landed

    const int arow0 = wm * 128;
    const int brow0 = (wn >> 1) * 128 + (wn & 1) * 64;
#pragma unroll
    for (int mi = 0; mi < 4; ++mi)
#pragma unroll
      for (int ks = 0; ks < 2; ++ks)
        af[mi][ks] = *(const short8*)&AL[(arow0 + mi * 16 + lo) * 64 +
                                         (((ks * 4 + hi) ^ (lo & 7)) * 8)];
#pragma unroll
    for (int ni = 0; ni < 2; ++ni)
#pragma unroll
      for (int ks = 0; ks < 2; ++ks)
        bfA[ni][ks] = *(const short8*)&BL[(brow0 + ni * 16 + lo) * 64 +
                                          (((ks * 4 + hi) ^ (lo & 7)) * 8)];
#pragma unroll
    for (int ni = 0; ni < 2; ++ni)
#pragma unroll
      for (int ks = 0; ks < 2; ++ks)
        bfB[ni][ks] = *(const short8*)&BL[(brow0 + 32 + ni * 16 + lo) * 64 +
                                          (((ks * 4 + hi) ^ (lo & 7)) * 8)];
    __builtin_amdgcn_s_setprio(1);
#pragma unroll
    for (int mi = 0; mi < 4; ++mi)
#pragma unroll
      for (int ni = 0; ni < 2; ++ni)
#pragma unroll
        for (int ks = 0; ks < 2; ++ks) {
          MFMA(acc[mi][ni], af[mi][ks], bfA[ni][ks]);
          MFMA(acc[mi][2 + ni], af[mi][ks], bfB[ni][ks]);
        }
    __builtin_amdgcn_s_setprio(0);
#pragma unroll
    for (int mi = 0; mi < 4; ++mi)
#pragma unroll
      for (int ks = 0; ks < 2; ++ks)
        af[mi][ks] = *(const short8*)&AL[(arow0 + 64 + mi * 16 + lo) * 64 +
                                         (((ks * 4 + hi) ^ (lo & 7)) * 8)];
    __builtin_amdgcn_s_setprio(1);
#pragma unroll
    for (int mi = 0; mi < 4; ++mi)
#pragma unroll
      for (int ni = 0; ni < 2; ++ni)
#pragma unroll
        for (int ks = 0; ks < 2; ++ks) {
          MFMA(acc[4 + mi][2 + ni], af[mi][ks], bfB[ni][ks]);
          MFMA(acc[4 + mi][ni], af[mi][ks], bfA[ni][ks]);
        }
    __builtin_amdgcn_s_setprio(0);
  }

  if constexpr (MODE == 1) {
#pragma unroll
    for (int mf = 0; mf < 8; ++mf)
#pragma unroll
      for (int nf = 0; nf < 4; ++nf)
#pragma unroll
        for (int j = 0; j < 4; ++j) {
          size_t idx = (size_t)(bm * 256 + wm * 128 + mf * 16 + hi * 4 + j) * N +
                       bn * 256 + wn * 64 + nf * 16 + lo;
          ((float*)C)[idx] = acc[mf][nf][j];
        }
  } else {
    // fused epilogue, 2 passes of 128 rows (E = 128x280 bf16, 70 KB)
    const int SP2 = 280;
    u16* E = SMEM;
    const int grow0 = bm * 256, gcol0 = bn * 256;
    const int bb = grow0 >> 11, s0 = grow0 & 2047;
#pragma unroll
    for (int h = 0; h < 2; ++h) {
      __syncthreads();  // K-loop reads / previous pass done
      if (wm == h) {
#pragma unroll
        for (int mf = 0; mf < 8; ++mf)
#pragma unroll
          for (int nf = 0; nf < 4; ++nf)
#pragma unroll
            for (int j = 0; j < 4; ++j)
              E[(mf * 16 + hi * 4 + j) * SP2 + wn * 64 + nf * 16 + lo] =
                  f2b(acc[mf][nf][j]);
      }
      __syncthreads();
      if (gcol0 < 8192) {
        // Q/K rope: 4096 tasks = 128 rows x 32 granules
        for (int task = tid; task < 4096; task += 512) {
          int row = task >> 5, g = task & 31;
          int gcol = gcol0 + g * 8;
          int d = gcol & 127, f0 = d & 63;
          int p = pos[grow0 + h * 128 + row];
          const float* cp = tab + (size_t)p * 128 + f0;
          float4 ca = *(const float4*)cp, cb = *(const float4*)(cp + 4);
          float4 sa = *(const float4*)(cp + 64), sb = *(const float4*)(cp + 68);
          float cv[8] = {ca.x, ca.y, ca.z, ca.w, cb.x, cb.y, cb.z, cb.w};
          float sv[8] = {sa.x, sa.y, sa.z, sa.w, sb.x, sb.y, sb.z, sb.w};
          short8 x = *(const short8*)&E[row * SP2 + g * 8];
          short8 xo = *(const short8*)&E[row * SP2 + (g ^ 8) * 8];
          float sgn = (d < 64) ? -1.0f : 1.0f;
          unsigned word[4];
#pragma unroll
          for (int pr = 0; pr < 4; ++pr) {
            float v0 = b2f((u16)x[2 * pr]) * cv[2 * pr] +
                       sgn * b2f((u16)xo[2 * pr]) * sv[2 * pr];
            float v1 = b2f((u16)x[2 * pr + 1]) * cv[2 * pr + 1] +
                       sgn * b2f((u16)xo[2 * pr + 1]) * sv[2 * pr + 1];
            word[pr] = (unsigned)f2b(v0) | ((unsigned)f2b(v1) << 16);
          }
          int hidx = gcol >> 7;
          u16* outp = (hidx < 32) ? qr : kr;
          int nh = (hidx < 32) ? hidx : hidx - 32;
          size_t dst = ((size_t)(bb * 32 + nh) * 2048 + (s0 + h * 128 + row)) * 128 + d;
          uint4 o = {word[0], word[1], word[2], word[3]};
          *(uint4*)&outp[dst] = o;
        }
      } else {
        // V fragment-order: 4096 tasks = 2 kbl2 x 2 heads x 1024 chunks
        for (int task = tid; task < 4096; task += 512) {
          int kbl2 = task >> 11;
          int hh = (task >> 10) & 1;
          int c = task & 1023;
          int f = c >> 6, l = c & 63;
          int ks2 = f >> 3, db = f & 7, hi2 = l >> 4, lo2 = l & 15;
          int base = (kbl2 * 64 + ks2 * 32 + hi2 * 8) * SP2 + hh * 128 + db * 16 + lo2;
          unsigned e0 = E[base], e1 = E[base + SP2], e2 = E[base + 2 * SP2],
                   e3 = E[base + 3 * SP2], e4 = E[base + 4 * SP2],
                   e5 = E[base + 5 * SP2], e6 = E[base + 6 * SP2],
                   e7 = E[base + 7 * SP2];
          int nh = ((gcol0 - 8192) >> 7) + hh;
          size_t dst = ((size_t)(bb * 32 + nh) * 2048 +
                        (s0 + (h * 2 + kbl2) * 64)) * 128 + (size_t)c * 8;
          uint4 o = {e0 | (e1 << 16), e2 | (e3 << 16), e4 | (e5 << 16),
                     e6 | (e7 << 16)};
          *(uint4*)&vt[dst] = o;
        }
      }
    }
  }
}

// ---- flash attention fwd, causal (r20 version: double-buffered DMA,
// counted vmcnt(8), base-2 softmax, deferred l-sum, uniform diag mask) ----
__global__ __launch_bounds__(256, 2) void flash_fwd(const u16* __restrict__ q,
                                                    const u16* __restrict__ k,
                                                    const u16* __restrict__ vt,
                                                    u16* __restrict__ o) {
  __shared__ u16 KB[2][64 * 128];
  __shared__ u16 VB[2][64 * 128];
  __shared__ u16 Ps[4][16 * 64];
  const int nqt = S / 64;
  const int qt = (nqt - 1) - ((int)blockIdx.x % nqt);
  const int bh = blockIdx.x / nqt;
  const int tid = threadIdx.x, lane = tid & 63, w = tid >> 6;
  const int hi = lane >> 4, lo = lane & 15;

  const u16* qg = q + ((size_t)bh * S + qt * 64 + w * 16) * HDIM;
  short8 qf[4];
#pragma unroll
  for (int ks = 0; ks < 4; ++ks) {
    short8 r = *(const short8*)(qg + (size_t)lo * HDIM + ks * 32 + hi * 8);
    union { short8 s; u16 u[8]; } t; t.s = r;
#pragma unroll
    for (int e = 0; e < 8; ++e)
      t.u[e] = f2b(b2f(t.u[e]) * 0.12751744534367265f);  // 128^-0.5 * log2(e)
    qf[ks] = t.s;
  }

  float m_i[4], lsum[4];
  f32x4 oacc[8] = {};
#pragma unroll
  for (int j = 0; j < 4; ++j) { m_i[j] = -1e30f; lsum[j] = 0.0f; }

  const u16* kg = k + (size_t)bh * S * HDIM;
  const u16* vg = vt + (size_t)bh * S * HDIM;

#define STAGE(buf, kvbase)                                                  \
  {                                                                         \
    _Pragma("unroll") for (int i = 0; i < 4; ++i) {                         \
      int idx = i * 256 + tid, r = idx >> 4, gd = idx & 15;                 \
      gl16(kg + (size_t)((kvbase) + r) * HDIM + ((gd ^ (r & 7)) * 8),       \
           &KB[buf][idx * 8]);                                              \
    }                                                                       \
    _Pragma("unroll") for (int i = 0; i < 4; ++i) {                         \
      int idx = i * 256 + tid;                                              \
      gl16(vg + (size_t)(kvbase) * HDIM + idx * 8, &VB[buf][idx * 8]);      \
    }                                                                       \
  }

  STAGE(0, 0)
  int cur = 0;
  u16* PsW = &Ps[w][0];

  for (int kvt = 0; kvt <= qt; ++kvt) {
    if (kvt < qt) {
      STAGE(cur ^ 1, (kvt + 1) * 64)
      asm volatile("s_waitcnt vmcnt(8)" ::: "memory");
    } else {
      asm volatile("s_waitcnt vmcnt(0)" ::: "memory");
    }
    __builtin_amdgcn_s_barrier();
    __builtin_amdgcn_sched_barrier(0);
    const u16* Kc = &KB[cur][0];
    const u16* Vc = &VB[cur][0];

    f32x4 sc[4] = {};
#pragma unroll
    for (int ks = 0; ks < 4; ++ks) {
      const int colu = ks * 32 + hi * 8;
#pragma unroll
      for (int cb = 0; cb < 4; ++cb) {
        const int row = cb * 16 + lo;
        short8 kf = *(const short8*)&Kc[row * 128 + (colu ^ ((row & 7) << 3))];
        MFMA(sc[cb], qf[ks], kf);
      }
    }

    if (kvt == qt) {  // uniform branch: only the diagonal tile masks
      const int qrow = qt * 64 + w * 16 + hi * 4;
#pragma unroll
      for (int cb = 0; cb < 4; ++cb) {
        const int kvc = kvt * 64 + cb * 16 + lo;
#pragma unroll
        for (int j = 0; j < 4; ++j)
          if (kvc > qrow + j) sc[cb][j] = -1e30f;
      }
    }
    float rmax[4];
#pragma unroll
    for (int j = 0; j < 4; ++j) {
      rmax[j] = fmaxf(fmaxf(sc[0][j], sc[1][j]), fmaxf(sc[2][j], sc[3][j]));
      for (int d = 8; d; d >>= 1) rmax[j] = fmaxf(rmax[j], __shfl_xor(rmax[j], d));
      float mn = fmaxf(m_i[j], rmax[j]);
      float sf = ex2(m_i[j] - mn);
      m_i[j] = mn; lsum[j] *= sf;
#pragma unroll
      for (int db = 0; db < 8; ++db) oacc[db][j] *= sf;
    }
#pragma unroll
    for (int cb = 0; cb < 4; ++cb)
#pragma unroll
      for (int j = 0; j < 4; ++j) {
        float p = ex2(sc[cb][j] - m_i[j]);
        sc[cb][j] = p; lsum[j] += p;  // per-lane partial; reduced in epilogue
      }

#pragma unroll
    for (int cb = 0; cb < 4; ++cb)
#pragma unroll
      for (int j = 0; j < 4; ++j) {
        const int p = hi * 4 + j;
        PsW[p * 64 + ((cb * 16 + lo) ^ ((p & 7) << 3))] = f2b(sc[cb][j]);
      }
    short8 pf0 = *(const short8*)&PsW[lo * 64 + ((hi * 8) ^ ((lo & 7) << 3))];
    short8 pf1 = *(const short8*)&PsW[lo * 64 + ((32 + hi * 8) ^ ((lo & 7) << 3))];

#pragma unroll
    for (int ks2 = 0; ks2 < 2; ++ks2) {
      const short8 pf = ks2 ? pf1 : pf0;
#pragma unroll
      for (int db = 0; db < 8; ++db) {
        short8 vf = *(const short8*)&Vc[((ks2 * 8 + db) * 64 + lane) * 8];
        MFMA(oacc[db], pf, vf);
      }
    }
    __builtin_amdgcn_s_barrier();
    cur ^= 1;
  }

#pragma unroll
  for (int j = 0; j < 4; ++j) {
    float l = lsum[j];
    for (int d = 8; d; d >>= 1) l += __shfl_xor(l, d);  // one tree, at the end
    float inv = 1.0f / l;
    int srow = qt * 64 + w * 16 + hi * 4 + j;
    const int b = bh >> 5, nh = bh & 31;
    size_t base = ((size_t)b * S + srow) * H + (size_t)nh * HDIM + lo;
#pragma unroll
    for (int db = 0; db < 8; ++db)
      o[base + db * 16] = f2b(oacc[db][j] * inv);
  }
}

extern "C" void kernel_launch(void* const* d_in, const int* in_sizes, int n_in,
                              void* d_out, int out_size, void* d_ws, size_t ws_size,
                              hipStream_t stream) {
  const int* pos = (const int*)d_in[0];
  const float* hs = (const float*)d_in[1];
  const float* wpack = (const float*)d_in[2];
  const float* wo = (const float*)d_in[3];
  float* out = (float*)d_out;
  char* ws = (char*)d_ws;
  u16* hs_b    = (u16*)(ws + 0UL);
  u16* wpack_b = (u16*)(ws + 33554432UL);
  u16* wo_b    = (u16*)(ws + 134217728UL);
  u16* v_t     = (u16*)(ws + 167772160UL);  // 32 MiB (old qkv region)
  float* tab   = (float*)(ws + 201326592UL);  // 1 MiB rope table
  u16* q_r     = (u16*)(ws + 268435456UL);
  u16* k_r     = (u16*)(ws + 301989888UL);
  u16* attn_b  = (u16*)(ws + 335544320UL);

  prep<<<82432, 256, 0, stream>>>(hs, wpack, wo, hs_b, wpack_b, wo_b, tab);
  gemm256<0><<<768, 512, 0, stream>>>(hs_b, wpack_b, nullptr, 4096, 12288, 4096,
                                      pos, tab, q_r, k_r, v_t);
  flash_fwd<<<64 * 32, 256, 0, stream>>>(q_r, k_r, v_t, attn_b);
  gemm256<1><<<256, 512, 0, stream>>>(attn_b, wo_b, out, 4096, 4096, 4096,
                                      nullptr, nullptr, nullptr, nullptr, nullptr);
}

// Round 23
// 808.443 us; speedup vs baseline: 5.7202x; 5.7202x over previous
//
#include <hip/hip_runtime.h>

typedef short short8 __attribute__((ext_vector_type(8)));
typedef float f32x4 __attribute__((ext_vector_type(4)));
typedef unsigned short u16;

static constexpr int BATCH = 2, S = 2048, H = 4096, NHEAD = 32, HDIM = 128;

__device__ __forceinline__ u16 f2b(float f) {
  union { float f; unsigned u; } v; v.f = f;
  return (u16)((v.u + 0x7fffu + ((v.u >> 16) & 1u)) >> 16);
}
__device__ __forceinline__ float b2f(u16 h) {
  union { unsigned u; float f; } v; v.u = ((unsigned)h) << 16;
  return v.f;
}
__device__ __forceinline__ float ex2(float x) {
  return __builtin_amdgcn_exp2f(x);  // v_exp_f32 (base-2 HW exp)
}

__device__ __forceinline__ void gl16(const u16* g, u16* l) {
  __builtin_amdgcn_global_load_lds((__attribute__((address_space(1))) void*)g,
                                   (__attribute__((address_space(3))) void*)l,
                                   16, 0, 0);
}

#define MFMA(acc, a, b) \
  acc = __builtin_amdgcn_mfma_f32_16x16x32_bf16(a, b, acc, 0, 0, 0)

// ---- merged prep: 3x f32->bf16 convert + RoPE table (one launch) ----
__global__ __launch_bounds__(256) void prep(const float* __restrict__ hs,
                                            const float* __restrict__ wpack,
                                            const float* __restrict__ wo,
                                            u16* __restrict__ hs_b,
                                            u16* __restrict__ wpack_b,
                                            u16* __restrict__ wo_b,
                                            float* __restrict__ tab) {
  int b = blockIdx.x;
  if (b < 81920) {
    const float* in; u16* out; size_t off;
    if (b < 16384)      { in = hs;    out = hs_b;    off = (size_t)b * 1024; }
    else if (b < 65536) { in = wpack; out = wpack_b; off = (size_t)(b - 16384) * 1024; }
    else                { in = wo;    out = wo_b;    off = (size_t)(b - 65536) * 1024; }
    size_t i = off + threadIdx.x * 4;
    float4 v = *(const float4*)(in + i);
    ushort4 o = { f2b(v.x), f2b(v.y), f2b(v.z), f2b(v.w) };
    *(ushort4*)(out + i) = o;
  } else {
    int idx = (b - 81920) * 256 + threadIdx.x;  // 512*256 = 2048*64
    int p = idx >> 6, f = idx & 63;
    float freq = __powf(10000.0f, -(float)f * (1.0f / 64.0f));
    float a = (float)p * freq;
    tab[(size_t)p * 128 + f] = cosf(a);
    tab[(size_t)p * 128 + 64 + f] = sinf(a);
  }
}

// ---- 256x256 NT GEMM, 4 phases/K-tile, BK=64, 8 waves (2x4). r16 schedule
// (skewed consumption, converged at ~1036 TF / MfmaUtil 46). Register-bound
// at 1 block/CU (acc 128 AGPR + ~116 VGPR) — occupancy axis closed (r22).
// MODE 0: fused RoPE/V-scatter epilogue. MODE 1: plain f32 C.
template <int MODE>
__global__ __launch_bounds__(512, 2) void gemm256(
    const u16* __restrict__ A, const u16* __restrict__ B, void* __restrict__ C,
    int M, int N, int K, const int* __restrict__ pos,
    const float* __restrict__ tab, u16* __restrict__ qr, u16* __restrict__ kr,
    u16* __restrict__ vt) {
  __shared__ u16 SMEM[69632];  // GEMM: AL 64KB + BL 64KB; epilogue: E 256x272
  u16* AL = SMEM;              // [(buf*2+half)*8192 + c*8]
  u16* BL = SMEM + 32768;
  const int nbn = N >> 8;
  const int nwg = (M >> 8) * nbn;
  const int bid = blockIdx.x;
  const int wg = (bid & 7) * (nwg >> 3) + (bid >> 3);  // XCD swizzle (nwg%8==0)
  const int bm = wg / nbn, bn = wg % nbn;
  const int tid = threadIdx.x, lane = tid & 63;
  const int w = tid >> 6, wm = w >> 2, wn = w & 3;
  const int hi = lane >> 4, lo = lane & 15;
  const int nk = K >> 6;

  const u16* Abase = A + (size_t)(bm * 256) * K;
  const u16* Bbase = B + (size_t)(bn * 256) * K;

#define STG_A(buf, half, kt)                                                   \
  { _Pragma("unroll") for (int i = 0; i < 2; ++i) {                            \
      int c = tid + i * 512, r = c >> 3, s = c & 7;                            \
      gl16(Abase + (size_t)((half) * 128 + r) * K + (kt) * 64 +                \
               ((s ^ (r & 7)) * 8),                                            \
           &AL[((buf) * 2 + (half)) * 8192 + c * 8]);                          \
    } }
#define STG_B(buf, half, kt)                                                   \
  { _Pragma("unroll") for (int i = 0; i < 2; ++i) {                            \
      int c = tid + i * 512, r = c >> 3, s = c & 7;                            \
      gl16(Bbase + (size_t)((half) * 128 + r) * K + (kt) * 64 +                \
               ((s ^ (r & 7)) * 8),                                            \
           &BL[((buf) * 2 + (half)) * 8192 + c * 8]);                          \
    } }
#define BARTOP()                                                               \
  do { __builtin_amdgcn_s_barrier();                                           \
       __builtin_amdgcn_sched_barrier(0); } while (0)

  f32x4 acc[8][4] = {};

  STG_A(0, 0, 0) STG_A(0, 1, 0) STG_B(0, 0, 0) STG_B(0, 1, 0)
  if (nk > 1) {
    STG_B(1, 0, 1) STG_B(1, 1, 1)
    asm volatile("s_waitcnt vmcnt(4)" ::: "memory");
  } else {
    asm volatile("s_waitcnt vmcnt(0)" ::: "memory");
  }
  __builtin_amdgcn_sched_barrier(0);

  short8 af[4][2], bfA[2][2], bfB[2][2];

  for (int t = 0; t < nk; ++t) {
    const int cur = t & 1;
    const u16* Awave = AL + (cur * 2 + wm) * 8192;
    const u16* Bwave = BL + (cur * 2 + (wn >> 1)) * 8192;
    const int lrB = (wn & 1) * 64;

    // F1: reads only (af mh0, bfA nh0); stage A0(t+1)
    BARTOP();
    if (t + 1 < nk) STG_A(cur ^ 1, 0, t + 1)
#pragma unroll
    for (int mi = 0; mi < 4; ++mi)
#pragma unroll
      for (int ks = 0; ks < 2; ++ks)
        af[mi][ks] = *(const short8*)&Awave[(mi * 16 + lo) * 64 +
                                            (((ks * 4 + hi) ^ (lo & 7)) * 8)];
#pragma unroll
    for (int ni = 0; ni < 2; ++ni)
#pragma unroll
      for (int ks = 0; ks < 2; ++ks)
        bfA[ni][ks] = *(const short8*)&Bwave[(lrB + ni * 16 + lo) * 64 +
                                             (((ks * 4 + hi) ^ (lo & 7)) * 8)];

    // F2: reads bfB || MFMA q1; stage A1(t+1)
    BARTOP();
    if (t + 1 < nk) STG_A(cur ^ 1, 1, t + 1)
#pragma unroll
    for (int ni = 0; ni < 2; ++ni)
#pragma unroll
      for (int ks = 0; ks < 2; ++ks)
        bfB[ni][ks] = *(const short8*)&Bwave[(lrB + 32 + ni * 16 + lo) * 64 +
                                             (((ks * 4 + hi) ^ (lo & 7)) * 8)];
    __builtin_amdgcn_s_setprio(1);
#pragma unroll
    for (int mi = 0; mi < 4; ++mi)
#pragma unroll
      for (int ni = 0; ni < 2; ++ni)
#pragma unroll
        for (int ks = 0; ks < 2; ++ks)
          MFMA(acc[mi][ni], af[mi][ks], bfA[ni][ks]);
    __builtin_amdgcn_s_setprio(0);

    // F3: MFMA q2; re-read af <- mh1; stage B0(t+2)
    BARTOP();
    if (t + 2 < nk) STG_B(cur, 0, t + 2)
    __builtin_amdgcn_s_setprio(1);
#pragma unroll
    for (int mi = 0; mi < 4; ++mi)
#pragma unroll
      for (int ni = 0; ni < 2; ++ni)
#pragma unroll
        for (int ks = 0; ks < 2; ++ks)
          MFMA(acc[mi][2 + ni], af[mi][ks], bfB[ni][ks]);
    __builtin_amdgcn_s_setprio(0);
#pragma unroll
    for (int mi = 0; mi < 4; ++mi)
#pragma unroll
      for (int ks = 0; ks < 2; ++ks)
        af[mi][ks] = *(const short8*)&Awave[((64 + mi * 16 + lo)) * 64 +
                                            (((ks * 4 + hi) ^ (lo & 7)) * 8)];

    // F4: MFMA q3 + q4; stage B1(t+2); counted vmcnt
    BARTOP();
    if (t + 2 < nk) STG_B(cur, 1, t + 2)
    __builtin_amdgcn_s_setprio(1);
#pragma unroll
    for (int mi = 0; mi < 4; ++mi)
#pragma unroll
      for (int ni = 0; ni < 2; ++ni)
#pragma unroll
        for (int ks = 0; ks < 2; ++ks)
          MFMA(acc[4 + mi][2 + ni], af[mi][ks], bfB[ni][ks]);
#pragma unroll
    for (int mi = 0; mi < 4; ++mi)
#pragma unroll
      for (int ni = 0; ni < 2; ++ni)
#pragma unroll
        for (int ks = 0; ks < 2; ++ks)
          MFMA(acc[4 + mi][ni], af[mi][ks], bfA[ni][ks]);
    __builtin_amdgcn_s_setprio(0);
    if (t + 2 < nk) {
      asm volatile("s_waitcnt vmcnt(4)" ::: "memory");
    } else {
      asm volatile("s_waitcnt vmcnt(0)" ::: "memory");
    }
    __builtin_amdgcn_sched_barrier(0);
  }

  if constexpr (MODE == 1) {
#pragma unroll
    for (int mf = 0; mf < 8; ++mf)
#pragma unroll
      for (int nf = 0; nf < 4; ++nf)
#pragma unroll
        for (int j = 0; j < 4; ++j) {
          size_t idx = (size_t)(bm * 256 + wm * 128 + mf * 16 + hi * 4 + j) * N +
                       bn * 256 + wn * 64 + nf * 16 + lo;
          ((float*)C)[idx] = acc[mf][nf][j];
        }
  } else {
    const int SP = 272;
    u16* E = SMEM;
    __syncthreads();
#pragma unroll
    for (int mf = 0; mf < 8; ++mf)
#pragma unroll
      for (int nf = 0; nf < 4; ++nf)
#pragma unroll
        for (int j = 0; j < 4; ++j)
          E[(wm * 128 + mf * 16 + hi * 4 + j) * SP + wn * 64 + nf * 16 + lo] =
              f2b(acc[mf][nf][j]);
    __syncthreads();

    const int grow0 = bm * 256, gcol0 = bn * 256;
    const int bb = grow0 >> 11, s0 = grow0 & 2047;
    if (gcol0 < 8192) {
      for (int task = tid; task < 8192; task += 512) {
        int row = task >> 5, g = task & 31;
        int gcol = gcol0 + g * 8;
        int d = gcol & 127, f0 = d & 63;
        int p = pos[grow0 + row];
        const float* cp = tab + (size_t)p * 128 + f0;
        float4 ca = *(const float4*)cp, cb = *(const float4*)(cp + 4);
        float4 sa = *(const float4*)(cp + 64), sb = *(const float4*)(cp + 68);
        float cv[8] = {ca.x, ca.y, ca.z, ca.w, cb.x, cb.y, cb.z, cb.w};
        float sv[8] = {sa.x, sa.y, sa.z, sa.w, sb.x, sb.y, sb.z, sb.w};
        short8 x = *(const short8*)&E[row * SP + g * 8];
        short8 xo = *(const short8*)&E[row * SP + (g ^ 8) * 8];
        float sgn = (d < 64) ? -1.0f : 1.0f;
        unsigned word[4];
#pragma unroll
        for (int pr = 0; pr < 4; ++pr) {
          float v0 = b2f((u16)x[2 * pr]) * cv[2 * pr] +
                     sgn * b2f((u16)xo[2 * pr]) * sv[2 * pr];
          float v1 = b2f((u16)x[2 * pr + 1]) * cv[2 * pr + 1] +
                     sgn * b2f((u16)xo[2 * pr + 1]) * sv[2 * pr + 1];
          word[pr] = (unsigned)f2b(v0) | ((unsigned)f2b(v1) << 16);
        }
        int hidx = gcol >> 7;
        u16* outp = (hidx < 32) ? qr : kr;
        int nh = (hidx < 32) ? hidx : hidx - 32;
        size_t dst = ((size_t)(bb * 32 + nh) * 2048 + (s0 + row)) * 128 + d;
        uint4 o = {word[0], word[1], word[2], word[3]};
        *(uint4*)&outp[dst] = o;
      }
    } else {
      for (int task = tid; task < 8192; task += 512) {
        int kbl = task >> 11;
        int hh = (task >> 10) & 1;
        int c = task & 1023;
        int f = c >> 6, l = c & 63;
        int ks2 = f >> 3, db = f & 7, hi2 = l >> 4, lo2 = l & 15;
        int base = (kbl * 64 + ks2 * 32 + hi2 * 8) * SP + hh * 128 + db * 16 + lo2;
        unsigned e0 = E[base], e1 = E[base + SP], e2 = E[base + 2 * SP],
                 e3 = E[base + 3 * SP], e4 = E[base + 4 * SP],
                 e5 = E[base + 5 * SP], e6 = E[base + 6 * SP],
                 e7 = E[base + 7 * SP];
        int nh = ((gcol0 - 8192) >> 7) + hh;
        size_t dst = ((size_t)(bb * 32 + nh) * 2048 + (s0 + kbl * 64)) * 128 +
                     (size_t)c * 8;
        uint4 o = {e0 | (e1 << 16), e2 | (e3 << 16), e4 | (e5 << 16),
                   e6 | (e7 << 16)};
        *(uint4*)&vt[dst] = o;
      }
    }
  }
}

// ---- flash attention fwd, causal (r20: double-buffered DMA, counted
// vmcnt(8), base-2 softmax, deferred l-sum, uniform diag mask) ----
__global__ __launch_bounds__(256, 2) void flash_fwd(const u16* __restrict__ q,
                                                    const u16* __restrict__ k,
                                                    const u16* __restrict__ vt,
                                                    u16* __restrict__ o) {
  __shared__ u16 KB[2][64 * 128];
  __shared__ u16 VB[2][64 * 128];
  __shared__ u16 Ps[4][16 * 64];
  const int nqt = S / 64;
  const int qt = (nqt - 1) - ((int)blockIdx.x % nqt);
  const int bh = blockIdx.x / nqt;
  const int tid = threadIdx.x, lane = tid & 63, w = tid >> 6;
  const int hi = lane >> 4, lo = lane & 15;

  const u16* qg = q + ((size_t)bh * S + qt * 64 + w * 16) * HDIM;
  short8 qf[4];
#pragma unroll
  for (int ks = 0; ks < 4; ++ks) {
    short8 r = *(const short8*)(qg + (size_t)lo * HDIM + ks * 32 + hi * 8);
    union { short8 s; u16 u[8]; } t; t.s = r;
#pragma unroll
    for (int e = 0; e < 8; ++e)
      t.u[e] = f2b(b2f(t.u[e]) * 0.12751744534367265f);  // 128^-0.5 * log2(e)
    qf[ks] = t.s;
  }

  float m_i[4], lsum[4];
  f32x4 oacc[8] = {};
#pragma unroll
  for (int j = 0; j < 4; ++j) { m_i[j] = -1e30f; lsum[j] = 0.0f; }

  const u16* kg = k + (size_t)bh * S * HDIM;
  const u16* vg = vt + (size_t)bh * S * HDIM;

#define STAGE(buf, kvbase)                                                  \
  {                                                                         \
    _Pragma("unroll") for (int i = 0; i < 4; ++i) {                         \
      int idx = i * 256 + tid, r = idx >> 4, gd = idx & 15;                 \
      gl16(kg + (size_t)((kvbase) + r) * HDIM + ((gd ^ (r & 7)) * 8),       \
           &KB[buf][idx * 8]);                                              \
    }                                                                       \
    _Pragma("unroll") for (int i = 0; i < 4; ++i) {                         \
      int idx = i * 256 + tid;                                              \
      gl16(vg + (size_t)(kvbase) * HDIM + idx * 8, &VB[buf][idx * 8]);      \
    }                                                                       \
  }

  STAGE(0, 0)
  int cur = 0;
  u16* PsW = &Ps[w][0];

  for (int kvt = 0; kvt <= qt; ++kvt) {
    if (kvt < qt) {
      STAGE(cur ^ 1, (kvt + 1) * 64)
      asm volatile("s_waitcnt vmcnt(8)" ::: "memory");
    } else {
      asm volatile("s_waitcnt vmcnt(0)" ::: "memory");
    }
    __builtin_amdgcn_s_barrier();
    __builtin_amdgcn_sched_barrier(0);
    const u16* Kc = &KB[cur][0];
    const u16* Vc = &VB[cur][0];

    f32x4 sc[4] = {};
#pragma unroll
    for (int ks = 0; ks < 4; ++ks) {
      const int colu = ks * 32 + hi * 8;
#pragma unroll
      for (int cb = 0; cb < 4; ++cb) {
        const int row = cb * 16 + lo;
        short8 kf = *(const short8*)&Kc[row * 128 + (colu ^ ((row & 7) << 3))];
        MFMA(sc[cb], qf[ks], kf);
      }
    }

    if (kvt == qt) {  // uniform branch: only the diagonal tile masks
      const int qrow = qt * 64 + w * 16 + hi * 4;
#pragma unroll
      for (int cb = 0; cb < 4; ++cb) {
        const int kvc = kvt * 64 + cb * 16 + lo;
#pragma unroll
        for (int j = 0; j < 4; ++j)
          if (kvc > qrow + j) sc[cb][j] = -1e30f;
      }
    }
    float rmax[4];
#pragma unroll
    for (int j = 0; j < 4; ++j) {
      rmax[j] = fmaxf(fmaxf(sc[0][j], sc[1][j]), fmaxf(sc[2][j], sc[3][j]));
      for (int d = 8; d; d >>= 1) rmax[j] = fmaxf(rmax[j], __shfl_xor(rmax[j], d));
      float mn = fmaxf(m_i[j], rmax[j]);
      float sf = ex2(m_i[j] - mn);
      m_i[j] = mn; lsum[j] *= sf;
#pragma unroll
      for (int db = 0; db < 8; ++db) oacc[db][j] *= sf;
    }
#pragma unroll
    for (int cb = 0; cb < 4; ++cb)
#pragma unroll
      for (int j = 0; j < 4; ++j) {
        float p = ex2(sc[cb][j] - m_i[j]);
        sc[cb][j] = p; lsum[j] += p;  // per-lane partial; reduced in epilogue
      }

#pragma unroll
    for (int cb = 0; cb < 4; ++cb)
#pragma unroll
      for (int j = 0; j < 4; ++j) {
        const int p = hi * 4 + j;
        PsW[p * 64 + ((cb * 16 + lo) ^ ((p & 7) << 3))] = f2b(sc[cb][j]);
      }
    short8 pf0 = *(const short8*)&PsW[lo * 64 + ((hi * 8) ^ ((lo & 7) << 3))];
    short8 pf1 = *(const short8*)&PsW[lo * 64 + ((32 + hi * 8) ^ ((lo & 7) << 3))];

#pragma unroll
    for (int ks2 = 0; ks2 < 2; ++ks2) {
      const short8 pf = ks2 ? pf1 : pf0;
#pragma unroll
      for (int db = 0; db < 8; ++db) {
        short8 vf = *(const short8*)&Vc[((ks2 * 8 + db) * 64 + lane) * 8];
        MFMA(oacc[db], pf, vf);
      }
    }
    __builtin_amdgcn_s_barrier();
    cur ^= 1;
  }

#pragma unroll
  for (int j = 0; j < 4; ++j) {
    float l = lsum[j];
    for (int d = 8; d; d >>= 1) l += __shfl_xor(l, d);  // one tree, at the end
    float inv = 1.0f / l;
    int srow = qt * 64 + w * 16 + hi * 4 + j;
    const int b = bh >> 5, nh = bh & 31;
    size_t base = ((size_t)b * S + srow) * H + (size_t)nh * HDIM + lo;
#pragma unroll
    for (int db = 0; db < 8; ++db)
      o[base + db * 16] = f2b(oacc[db][j] * inv);
  }
}

extern "C" void kernel_launch(void* const* d_in, const int* in_sizes, int n_in,
                              void* d_out, int out_size, void* d_ws, size_t ws_size,
                              hipStream_t stream) {
  const int* pos = (const int*)d_in[0];
  const float* hs = (const float*)d_in[1];
  const float* wpack = (const float*)d_in[2];
  const float* wo = (const float*)d_in[3];
  float* out = (float*)d_out;
  char* ws = (char*)d_ws;
  u16* hs_b    = (u16*)(ws + 0UL);
  u16* wpack_b = (u16*)(ws + 33554432UL);
  u16* wo_b    = (u16*)(ws + 134217728UL);
  u16* v_t     = (u16*)(ws + 167772160UL);  // 32 MiB (old qkv region)
  float* tab   = (float*)(ws + 201326592UL);  // 1 MiB rope table
  u16* q_r     = (u16*)(ws + 268435456UL);
  u16* k_r     = (u16*)(ws + 301989888UL);
  u16* attn_b  = (u16*)(ws + 335544320UL);

  prep<<<82432, 256, 0, stream>>>(hs, wpack, wo, hs_b, wpack_b, wo_b, tab);
  gemm256<0><<<768, 512, 0, stream>>>(hs_b, wpack_b, nullptr, 4096, 12288, 4096,
                                      pos, tab, q_r, k_r, v_t);
  flash_fwd<<<64 * 32, 256, 0, stream>>>(q_r, k_r, v_t, attn_b);
  gemm256<1><<<256, 512, 0, stream>>>(attn_b, wo_b, out, 4096, 4096, 4096,
                                      nullptr, nullptr, nullptr, nullptr, nullptr);
}

// Round 24
// 807.895 us; speedup vs baseline: 5.7241x; 1.0007x over previous
//
#include <hip/hip_runtime.h>

typedef short short8 __attribute__((ext_vector_type(8)));
typedef float f32x4 __attribute__((ext_vector_type(4)));
typedef unsigned short u16;

static constexpr int BATCH = 2, S = 2048, H = 4096, NHEAD = 32, HDIM = 128;

__device__ __forceinline__ u16 f2b(float f) {
  union { float f; unsigned u; } v; v.f = f;
  return (u16)((v.u + 0x7fffu + ((v.u >> 16) & 1u)) >> 16);
}
__device__ __forceinline__ float b2f(u16 h) {
  union { unsigned u; float f; } v; v.u = ((unsigned)h) << 16;
  return v.f;
}
__device__ __forceinline__ float ex2(float x) {
  return __builtin_amdgcn_exp2f(x);  // v_exp_f32 (base-2 HW exp)
}

__device__ __forceinline__ void gl16(const u16* g, u16* l) {
  __builtin_amdgcn_global_load_lds((__attribute__((address_space(1))) void*)g,
                                   (__attribute__((address_space(3))) void*)l,
                                   16, 0, 0);
}

#define MFMA(acc, a, b) \
  acc = __builtin_amdgcn_mfma_f32_16x16x32_bf16(a, b, acc, 0, 0, 0)

// ---- merged prep: 3x f32->bf16 convert + RoPE table (one launch) ----
__global__ __launch_bounds__(256) void prep(const float* __restrict__ hs,
                                            const float* __restrict__ wpack,
                                            const float* __restrict__ wo,
                                            u16* __restrict__ hs_b,
                                            u16* __restrict__ wpack_b,
                                            u16* __restrict__ wo_b,
                                            float* __restrict__ tab) {
  int b = blockIdx.x;
  if (b < 81920) {
    const float* in; u16* out; size_t off;
    if (b < 16384)      { in = hs;    out = hs_b;    off = (size_t)b * 1024; }
    else if (b < 65536) { in = wpack; out = wpack_b; off = (size_t)(b - 16384) * 1024; }
    else                { in = wo;    out = wo_b;    off = (size_t)(b - 65536) * 1024; }
    size_t i = off + threadIdx.x * 4;
    float4 v = *(const float4*)(in + i);
    ushort4 o = { f2b(v.x), f2b(v.y), f2b(v.z), f2b(v.w) };
    *(ushort4*)(out + i) = o;
  } else {
    int idx = (b - 81920) * 256 + threadIdx.x;  // 512*256 = 2048*64
    int p = idx >> 6, f = idx & 63;
    float freq = __powf(10000.0f, -(float)f * (1.0f / 64.0f));
    float a = (float)p * freq;
    tab[(size_t)p * 128 + f] = cosf(a);
    tab[(size_t)p * 128 + 64 + f] = sinf(a);
  }
}

// ---- 256x256 NT GEMM, 4 phases/K-tile, BK=64, 8 waves (2x4). r16 schedule
// (skewed consumption). r24: K-loop unrolled x2 so cur=t&1 constant-folds
// (static LDS bases, less per-iter VALU). Register-bound at 1 block/CU.
// MODE 0: fused RoPE/V-scatter epilogue. MODE 1: plain f32 C.
template <int MODE>
__global__ __launch_bounds__(512, 2) void gemm256(
    const u16* __restrict__ A, const u16* __restrict__ B, void* __restrict__ C,
    int M, int N, int K, const int* __restrict__ pos,
    const float* __restrict__ tab, u16* __restrict__ qr, u16* __restrict__ kr,
    u16* __restrict__ vt) {
  __shared__ u16 SMEM[69632];  // GEMM: AL 64KB + BL 64KB; epilogue: E 256x272
  u16* AL = SMEM;              // [(buf*2+half)*8192 + c*8]
  u16* BL = SMEM + 32768;
  const int nbn = N >> 8;
  const int nwg = (M >> 8) * nbn;
  const int bid = blockIdx.x;
  const int wg = (bid & 7) * (nwg >> 3) + (bid >> 3);  // XCD swizzle (nwg%8==0)
  const int bm = wg / nbn, bn = wg % nbn;
  const int tid = threadIdx.x, lane = tid & 63;
  const int w = tid >> 6, wm = w >> 2, wn = w & 3;
  const int hi = lane >> 4, lo = lane & 15;
  const int nk = K >> 6;

  const u16* Abase = A + (size_t)(bm * 256) * K;
  const u16* Bbase = B + (size_t)(bn * 256) * K;

#define STG_A(buf, half, kt)                                                   \
  { _Pragma("unroll") for (int i = 0; i < 2; ++i) {                            \
      int c = tid + i * 512, r = c >> 3, s = c & 7;                            \
      gl16(Abase + (size_t)((half) * 128 + r) * K + (kt) * 64 +                \
               ((s ^ (r & 7)) * 8),                                            \
           &AL[((buf) * 2 + (half)) * 8192 + c * 8]);                          \
    } }
#define STG_B(buf, half, kt)                                                   \
  { _Pragma("unroll") for (int i = 0; i < 2; ++i) {                            \
      int c = tid + i * 512, r = c >> 3, s = c & 7;                            \
      gl16(Bbase + (size_t)((half) * 128 + r) * K + (kt) * 64 +                \
               ((s ^ (r & 7)) * 8),                                            \
           &BL[((buf) * 2 + (half)) * 8192 + c * 8]);                          \
    } }
#define BARTOP()                                                               \
  do { __builtin_amdgcn_s_barrier();                                           \
       __builtin_amdgcn_sched_barrier(0); } while (0)

  f32x4 acc[8][4] = {};

  STG_A(0, 0, 0) STG_A(0, 1, 0) STG_B(0, 0, 0) STG_B(0, 1, 0)
  if (nk > 1) {
    STG_B(1, 0, 1) STG_B(1, 1, 1)
    asm volatile("s_waitcnt vmcnt(4)" ::: "memory");
  } else {
    asm volatile("s_waitcnt vmcnt(0)" ::: "memory");
  }
  __builtin_amdgcn_sched_barrier(0);

  short8 af[4][2], bfA[2][2], bfB[2][2];

#pragma unroll 2
  for (int t = 0; t < nk; ++t) {
    const int cur = t & 1;  // constant under unroll-2
    const u16* Awave = AL + (cur * 2 + wm) * 8192;
    const u16* Bwave = BL + (cur * 2 + (wn >> 1)) * 8192;
    const int lrB = (wn & 1) * 64;

    // F1: reads only (af mh0, bfA nh0); stage A0(t+1)
    BARTOP();
    if (t + 1 < nk) STG_A(cur ^ 1, 0, t + 1)
#pragma unroll
    for (int mi = 0; mi < 4; ++mi)
#pragma unroll
      for (int ks = 0; ks < 2; ++ks)
        af[mi][ks] = *(const short8*)&Awave[(mi * 16 + lo) * 64 +
                                            (((ks * 4 + hi) ^ (lo & 7)) * 8)];
#pragma unroll
    for (int ni = 0; ni < 2; ++ni)
#pragma unroll
      for (int ks = 0; ks < 2; ++ks)
        bfA[ni][ks] = *(const short8*)&Bwave[(lrB + ni * 16 + lo) * 64 +
                                             (((ks * 4 + hi) ^ (lo & 7)) * 8)];

    // F2: reads bfB || MFMA q1; stage A1(t+1)
    BARTOP();
    if (t + 1 < nk) STG_A(cur ^ 1, 1, t + 1)
#pragma unroll
    for (int ni = 0; ni < 2; ++ni)
#pragma unroll
      for (int ks = 0; ks < 2; ++ks)
        bfB[ni][ks] = *(const short8*)&Bwave[(lrB + 32 + ni * 16 + lo) * 64 +
                                             (((ks * 4 + hi) ^ (lo & 7)) * 8)];
    __builtin_amdgcn_s_setprio(1);
#pragma unroll
    for (int mi = 0; mi < 4; ++mi)
#pragma unroll
      for (int ni = 0; ni < 2; ++ni)
#pragma unroll
        for (int ks = 0; ks < 2; ++ks)
          MFMA(acc[mi][ni], af[mi][ks], bfA[ni][ks]);
    __builtin_amdgcn_s_setprio(0);

    // F3: MFMA q2; re-read af <- mh1; stage B0(t+2)
    BARTOP();
    if (t + 2 < nk) STG_B(cur, 0, t + 2)
    __builtin_amdgcn_s_setprio(1);
#pragma unroll
    for (int mi = 0; mi < 4; ++mi)
#pragma unroll
      for (int ni = 0; ni < 2; ++ni)
#pragma unroll
        for (int ks = 0; ks < 2; ++ks)
          MFMA(acc[mi][2 + ni], af[mi][ks], bfB[ni][ks]);
    __builtin_amdgcn_s_setprio(0);
#pragma unroll
    for (int mi = 0; mi < 4; ++mi)
#pragma unroll
      for (int ks = 0; ks < 2; ++ks)
        af[mi][ks] = *(const short8*)&Awave[((64 + mi * 16 + lo)) * 64 +
                                            (((ks * 4 + hi) ^ (lo & 7)) * 8)];

    // F4: MFMA q3 + q4; stage B1(t+2); counted vmcnt
    BARTOP();
    if (t + 2 < nk) STG_B(cur, 1, t + 2)
    __builtin_amdgcn_s_setprio(1);
#pragma unroll
    for (int mi = 0; mi < 4; ++mi)
#pragma unroll
      for (int ni = 0; ni < 2; ++ni)
#pragma unroll
        for (int ks = 0; ks < 2; ++ks)
          MFMA(acc[4 + mi][2 + ni], af[mi][ks], bfB[ni][ks]);
#pragma unroll
    for (int mi = 0; mi < 4; ++mi)
#pragma unroll
      for (int ni = 0; ni < 2; ++ni)
#pragma unroll
        for (int ks = 0; ks < 2; ++ks)
          MFMA(acc[4 + mi][ni], af[mi][ks], bfA[ni][ks]);
    __builtin_amdgcn_s_setprio(0);
    if (t + 2 < nk) {
      asm volatile("s_waitcnt vmcnt(4)" ::: "memory");
    } else {
      asm volatile("s_waitcnt vmcnt(0)" ::: "memory");
    }
    __builtin_amdgcn_sched_barrier(0);
  }

  if constexpr (MODE == 1) {
#pragma unroll
    for (int mf = 0; mf < 8; ++mf)
#pragma unroll
      for (int nf = 0; nf < 4; ++nf)
#pragma unroll
        for (int j = 0; j < 4; ++j) {
          size_t idx = (size_t)(bm * 256 + wm * 128 + mf * 16 + hi * 4 + j) * N +
                       bn * 256 + wn * 64 + nf * 16 + lo;
          ((float*)C)[idx] = acc[mf][nf][j];
        }
  } else {
    const int SP = 272;
    u16* E = SMEM;
    __syncthreads();
#pragma unroll
    for (int mf = 0; mf < 8; ++mf)
#pragma unroll
      for (int nf = 0; nf < 4; ++nf)
#pragma unroll
        for (int j = 0; j < 4; ++j)
          E[(wm * 128 + mf * 16 + hi * 4 + j) * SP + wn * 64 + nf * 16 + lo] =
              f2b(acc[mf][nf][j]);
    __syncthreads();

    const int grow0 = bm * 256, gcol0 = bn * 256;
    const int bb = grow0 >> 11, s0 = grow0 & 2047;
    if (gcol0 < 8192) {
      for (int task = tid; task < 8192; task += 512) {
        int row = task >> 5, g = task & 31;
        int gcol = gcol0 + g * 8;
        int d = gcol & 127, f0 = d & 63;
        int p = pos[grow0 + row];
        const float* cp = tab + (size_t)p * 128 + f0;
        float4 ca = *(const float4*)cp, cb = *(const float4*)(cp + 4);
        float4 sa = *(const float4*)(cp + 64), sb = *(const float4*)(cp + 68);
        float cv[8] = {ca.x, ca.y, ca.z, ca.w, cb.x, cb.y, cb.z, cb.w};
        float sv[8] = {sa.x, sa.y, sa.z, sa.w, sb.x, sb.y, sb.z, sb.w};
        short8 x = *(const short8*)&E[row * SP + g * 8];
        short8 xo = *(const short8*)&E[row * SP + (g ^ 8) * 8];
        float sgn = (d < 64) ? -1.0f : 1.0f;
        unsigned word[4];
#pragma unroll
        for (int pr = 0; pr < 4; ++pr) {
          float v0 = b2f((u16)x[2 * pr]) * cv[2 * pr] +
                     sgn * b2f((u16)xo[2 * pr]) * sv[2 * pr];
          float v1 = b2f((u16)x[2 * pr + 1]) * cv[2 * pr + 1] +
                     sgn * b2f((u16)xo[2 * pr + 1]) * sv[2 * pr + 1];
          word[pr] = (unsigned)f2b(v0) | ((unsigned)f2b(v1) << 16);
        }
        int hidx = gcol >> 7;
        u16* outp = (hidx < 32) ? qr : kr;
        int nh = (hidx < 32) ? hidx : hidx - 32;
        size_t dst = ((size_t)(bb * 32 + nh) * 2048 + (s0 + row)) * 128 + d;
        uint4 o = {word[0], word[1], word[2], word[3]};
        *(uint4*)&outp[dst] = o;
      }
    } else {
      for (int task = tid; task < 8192; task += 512) {
        int kbl = task >> 11;
        int hh = (task >> 10) & 1;
        int c = task & 1023;
        int f = c >> 6, l = c & 63;
        int ks2 = f >> 3, db = f & 7, hi2 = l >> 4, lo2 = l & 15;
        int base = (kbl * 64 + ks2 * 32 + hi2 * 8) * SP + hh * 128 + db * 16 + lo2;
        unsigned e0 = E[base], e1 = E[base + SP], e2 = E[base + 2 * SP],
                 e3 = E[base + 3 * SP], e4 = E[base + 4 * SP],
                 e5 = E[base + 5 * SP], e6 = E[base + 6 * SP],
                 e7 = E[base + 7 * SP];
        int nh = ((gcol0 - 8192) >> 7) + hh;
        size_t dst = ((size_t)(bb * 32 + nh) * 2048 + (s0 + kbl * 64)) * 128 +
                     (size_t)c * 8;
        uint4 o = {e0 | (e1 << 16), e2 | (e3 << 16), e4 | (e5 << 16),
                   e6 | (e7 << 16)};
        *(uint4*)&vt[dst] = o;
      }
    }
  }
}

// ---- flash attention fwd, causal (r20 + unroll-2 kv loop so cur folds) ----
__global__ __launch_bounds__(256, 2) void flash_fwd(const u16* __restrict__ q,
                                                    const u16* __restrict__ k,
                                                    const u16* __restrict__ vt,
                                                    u16* __restrict__ o) {
  __shared__ u16 KB[2][64 * 128];
  __shared__ u16 VB[2][64 * 128];
  __shared__ u16 Ps[4][16 * 64];
  const int nqt = S / 64;
  const int qt = (nqt - 1) - ((int)blockIdx.x % nqt);
  const int bh = blockIdx.x / nqt;
  const int tid = threadIdx.x, lane = tid & 63, w = tid >> 6;
  const int hi = lane >> 4, lo = lane & 15;

  const u16* qg = q + ((size_t)bh * S + qt * 64 + w * 16) * HDIM;
  short8 qf[4];
#pragma unroll
  for (int ks = 0; ks < 4; ++ks) {
    short8 r = *(const short8*)(qg + (size_t)lo * HDIM + ks * 32 + hi * 8);
    union { short8 s; u16 u[8]; } t; t.s = r;
#pragma unroll
    for (int e = 0; e < 8; ++e)
      t.u[e] = f2b(b2f(t.u[e]) * 0.12751744534367265f);  // 128^-0.5 * log2(e)
    qf[ks] = t.s;
  }

  float m_i[4], lsum[4];
  f32x4 oacc[8] = {};
#pragma unroll
  for (int j = 0; j < 4; ++j) { m_i[j] = -1e30f; lsum[j] = 0.0f; }

  const u16* kg = k + (size_t)bh * S * HDIM;
  const u16* vg = vt + (size_t)bh * S * HDIM;

#define STAGE(buf, kvbase)                                                  \
  {                                                                         \
    _Pragma("unroll") for (int i = 0; i < 4; ++i) {                         \
      int idx = i * 256 + tid, r = idx >> 4, gd = idx & 15;                 \
      gl16(kg + (size_t)((kvbase) + r) * HDIM + ((gd ^ (r & 7)) * 8),       \
           &KB[buf][idx * 8]);                                              \
    }                                                                       \
    _Pragma("unroll") for (int i = 0; i < 4; ++i) {                         \
      int idx = i * 256 + tid;                                              \
      gl16(vg + (size_t)(kvbase) * HDIM + idx * 8, &VB[buf][idx * 8]);      \
    }                                                                       \
  }

  STAGE(0, 0)
  u16* PsW = &Ps[w][0];

#pragma unroll 2
  for (int kvt = 0; kvt <= qt; ++kvt) {
    const int cur = kvt & 1;  // constant under unroll-2
    if (kvt < qt) {
      STAGE(cur ^ 1, (kvt + 1) * 64)
      asm volatile("s_waitcnt vmcnt(8)" ::: "memory");
    } else {
      asm volatile("s_waitcnt vmcnt(0)" ::: "memory");
    }
    __builtin_amdgcn_s_barrier();
    __builtin_amdgcn_sched_barrier(0);
    const u16* Kc = &KB[cur][0];
    const u16* Vc = &VB[cur][0];

    f32x4 sc[4] = {};
#pragma unroll
    for (int ks = 0; ks < 4; ++ks) {
      const int colu = ks * 32 + hi * 8;
#pragma unroll
      for (int cb = 0; cb < 4; ++cb) {
        const int row = cb * 16 + lo;
        short8 kf = *(const short8*)&Kc[row * 128 + (colu ^ ((row & 7) << 3))];
        MFMA(sc[cb], qf[ks], kf);
      }
    }

    if (kvt == qt) {  // uniform branch: only the diagonal tile masks
      const int qrow = qt * 64 + w * 16 + hi * 4;
#pragma unroll
      for (int cb = 0; cb < 4; ++cb) {
        const int kvc = kvt * 64 + cb * 16 + lo;
#pragma unroll
        for (int j = 0; j < 4; ++j)
          if (kvc > qrow + j) sc[cb][j] = -1e30f;
      }
    }
    float rmax[4];
#pragma unroll
    for (int j = 0; j < 4; ++j) {
      rmax[j] = fmaxf(fmaxf(sc[0][j], sc[1][j]), fmaxf(sc[2][j], sc[3][j]));
      for (int d = 8; d; d >>= 1) rmax[j] = fmaxf(rmax[j], __shfl_xor(rmax[j], d));
      float mn = fmaxf(m_i[j], rmax[j]);
      float sf = ex2(m_i[j] - mn);
      m_i[j] = mn; lsum[j] *= sf;
#pragma unroll
      for (int db = 0; db < 8; ++db) oacc[db][j] *= sf;
    }
#pragma unroll
    for (int cb = 0; cb < 4; ++cb)
#pragma unroll
      for (int j = 0; j < 4; ++j) {
        float p = ex2(sc[cb][j] - m_i[j]);
        sc[cb][j] = p; lsum[j] += p;  // per-lane partial; reduced in epilogue
      }

#pragma unroll
    for (int cb = 0; cb < 4; ++cb)
#pragma unroll
      for (int j = 0; j < 4; ++j) {
        const int p = hi * 4 + j;
        PsW[p * 64 + ((cb * 16 + lo) ^ ((p & 7) << 3))] = f2b(sc[cb][j]);
      }
    short8 pf0 = *(const short8*)&PsW[lo * 64 + ((hi * 8) ^ ((lo & 7) << 3))];
    short8 pf1 = *(const short8*)&PsW[lo * 64 + ((32 + hi * 8) ^ ((lo & 7) << 3))];

#pragma unroll
    for (int ks2 = 0; ks2 < 2; ++ks2) {
      const short8 pf = ks2 ? pf1 : pf0;
#pragma unroll
      for (int db = 0; db < 8; ++db) {
        short8 vf = *(const short8*)&Vc[((ks2 * 8 + db) * 64 + lane) * 8];
        MFMA(oacc[db], pf, vf);
      }
    }
    __builtin_amdgcn_s_barrier();
  }

#pragma unroll
  for (int j = 0; j < 4; ++j) {
    float l = lsum[j];
    for (int d = 8; d; d >>= 1) l += __shfl_xor(l, d);  // one tree, at the end
    float inv = 1.0f / l;
    int srow = qt * 64 + w * 16 + hi * 4 + j;
    const int b = bh >> 5, nh = bh & 31;
    size_t base = ((size_t)b * S + srow) * H + (size_t)nh * HDIM + lo;
#pragma unroll
    for (int db = 0; db < 8; ++db)
      o[base + db * 16] = f2b(oacc[db][j] * inv);
  }
}

extern "C" void kernel_launch(void* const* d_in, const int* in_sizes, int n_in,
                              void* d_out, int out_size, void* d_ws, size_t ws_size,
                              hipStream_t stream) {
  const int* pos = (const int*)d_in[0];
  const float* hs = (const float*)d_in[1];
  const float* wpack = (const float*)d_in[2];
  const float* wo = (const float*)d_in[3];
  float* out = (float*)d_out;
  char* ws = (char*)d_ws;
  u16* hs_b    = (u16*)(ws + 0UL);
  u16* wpack_b = (u16*)(ws + 33554432UL);
  u16* wo_b    = (u16*)(ws + 134217728UL);
  u16* v_t     = (u16*)(ws + 167772160UL);  // 32 MiB (old qkv region)
  float* tab   = (float*)(ws + 201326592UL);  // 1 MiB rope table
  u16* q_r     = (u16*)(ws + 268435456UL);
  u16* k_r     = (u16*)(ws + 301989888UL);
  u16* attn_b  = (u16*)(ws + 335544320UL);

  prep<<<82432, 256, 0, stream>>>(hs, wpack, wo, hs_b, wpack_b, wo_b, tab);
  gemm256<0><<<768, 512, 0, stream>>>(hs_b, wpack_b, nullptr, 4096, 12288, 4096,
                                      pos, tab, q_r, k_r, v_t);
  flash_fwd<<<64 * 32, 256, 0, stream>>>(q_r, k_r, v_t, attn_b);
  gemm256<1><<<256, 512, 0, stream>>>(attn_b, wo_b, out, 4096, 4096, 4096,
                                      nullptr, nullptr, nullptr, nullptr, nullptr);
}